// Round 3
// baseline (40143.195 us; speedup 1.0000x reference)
//
#include <hip/hip_runtime.h>

// ============================================================================
// 2-layer GRU encoder (TF GRUCell), B=32, S=512, V=32000, E=256, U=1024.
//
//  * Split-fp16 MFMA (hi + 2^-12-scaled lo), fp32 accum -> ~2^-24 effective
//    operand precision. Round-1 (bf16): absmax 0.506; round-2 (fp16): 0.085 —
//    error scales with mantissa => numerics-driven coherent drift, so both
//    weights AND published activations are split. 3 MFMA passes:
//      hi_acc += Whi*Ahi ; mid_acc += Wlo'*Ahi ; mid_acc += Whi*Alo'
//    result = hi_acc + mid_acc*2^-12. (Wlo*Alo term ~2^-24, skipped.)
//  * ONE persistent kernel, both layers pipelined (L1 lags L0 by 1 step):
//    513 rounds x {phase A: gates -> r,u, publish (r*h)hi/lo | phase B:
//    candidate, h update, publish h hi/lo}. 32 WGs x 256 thr; WG w owns
//    hidden cols [64w,64w+64) of its layer -> u-gate + fp32 h stay in-WG.
//  * h0 publish is PARITY DOUBLE-BUFFERED: L1 phase B restages y0 from h0pub
//    while L0 phase B publishes the next h0 -> must target different buffers.
//  * Cross-WG pubs via relaxed AGENT-scope 8B atomics (LLC-coherent, no
//    cache-invalidating acquire). Global barrier: monotonic counter.
//  * Precise expf/tanhf (activation-fn error also accumulates coherently).
//  * Workspace: ~49.9 MB (packed hi/lo weights 40.9 MB + fp16 xe 8.4 MB).
// ============================================================================

#define B_ 32
#define S_ 512
#define E_ 256
#define U_ 1024
#define NWG 32
#define LDS_BYTES 155904  // A 131072 + hM 8320 + uB 8320 + pS 8192
#define LO_SCALE 4096.f
#define LO_INV 2.44140625e-4f

typedef unsigned long long u64;
typedef unsigned short u16;
typedef unsigned int u32;
typedef _Float16 f16x8 __attribute__((ext_vector_type(8)));
typedef float f32x4 __attribute__((ext_vector_type(4)));

#define MFMA(a, b, c) __builtin_amdgcn_mfma_f32_16x16x32_f16(a, b, c, 0, 0, 0)

union H16 { _Float16 h; u16 u; };

__device__ __forceinline__ u16 f2h(float f) { H16 c; c.h = (_Float16)f; return c.u; }
__device__ __forceinline__ void split16(float v, u16& hi, u16& lo) {
  H16 a; a.h = (_Float16)v; hi = a.u;
  H16 b; b.h = (_Float16)((v - (float)a.h) * LO_SCALE); lo = b.u;
}
__device__ __forceinline__ float sigm(float x) { return 1.f / (1.f + expf(-x)); }

__device__ __forceinline__ u64 aload(const u64* p) {
  return __hip_atomic_load((u64*)p, __ATOMIC_RELAXED, __HIP_MEMORY_SCOPE_AGENT);
}
__device__ __forceinline__ void astore(u64* p, u64 v) {
  __hip_atomic_store(p, v, __ATOMIC_RELAXED, __HIP_MEMORY_SCOPE_AGENT);
}

#define SWZ_X(r) (((r) & 7) << 4)  // LDS XOR swizzle: kills 16-way ds_read_b128 bank conflicts

__device__ __forceinline__ void gbar(u32* cnt, unsigned& tgt) {
  __syncthreads();  // drains vmcnt: publishes visible at LLC
  if (threadIdx.x == 0) {
    __hip_atomic_fetch_add(cnt, 1u, __ATOMIC_RELEASE, __HIP_MEMORY_SCOPE_AGENT);
    while (__hip_atomic_load(cnt, __ATOMIC_RELAXED, __HIP_MEMORY_SCOPE_AGENT) < tgt) {}
  }
  tgt += NWG;
  __syncthreads();
  __atomic_signal_fence(__ATOMIC_ACQUIRE);
}

// Stage 32 rows x 1024 fp16 from a publish array into A-tile at byte col kofs.
__device__ __forceinline__ void stage_pub(char* A, const u64* pub, int kofs, int tid) {
  for (int i = tid; i < 4096; i += 256) {
    int r = i >> 7, c = i & 127;
    ulonglong2 v;
    v.x = aload(pub + (size_t)i * 2);
    v.y = aload(pub + (size_t)i * 2 + 1);
    *(ulonglong2*)(A + ((r * 4096 + kofs + c * 16) ^ SWZ_X(r))) = v;
  }
}

// ---------------------------------------------------------------------------
// Prep kernels
// ---------------------------------------------------------------------------
__global__ void init_ws_kernel(u32* cnt) {
  if (threadIdx.x == 0) *cnt = 0;
}

// Pack fp32 row-major W[K][N] into fragment-major fp16 hi + scaled-lo blocks.
// frag (nt,kc): 64 lanes x 16B; lane supplies B[k0+j][nt*16+(lane&15)],
// k0 = kc*32 + 8*(lane>>4), j=0..7 (B-operand of mfma_f32_16x16x32_f16).
__global__ void pack_w_kernel(const float* __restrict__ src, u64* __restrict__ dhi,
                              u64* __restrict__ dlo, int K, int N) {
  int wid = blockIdx.x * 4 + (threadIdx.x >> 6);
  int kcs = K >> 5;
  int ntt = N >> 4;
  if (wid >= ntt * kcs) return;
  int nt = wid / kcs, kc = wid - nt * kcs;
  int lane = threadIdx.x & 63;
  int col = nt * 16 + (lane & 15);
  int k0 = kc * 32 + ((lane >> 4) << 3);
  u64 h0 = 0, h1 = 0, l0 = 0, l1 = 0;
#pragma unroll
  for (int j = 0; j < 4; ++j) {
    float w = src[(size_t)(k0 + j) * N + col];
    u16 hb, lb; split16(w, hb, lb);
    h0 |= (u64)hb << (16 * j); l0 |= (u64)lb << (16 * j);
  }
#pragma unroll
  for (int j = 0; j < 4; ++j) {
    float w = src[(size_t)(k0 + 4 + j) * N + col];
    u16 hb, lb; split16(w, hb, lb);
    h1 |= (u64)hb << (16 * j); l1 |= (u64)lb << (16 * j);
  }
  size_t o = (size_t)(wid * 64 + lane) * 2;
  dhi[o] = h0; dhi[o + 1] = h1;
  dlo[o] = l0; dlo[o + 1] = l1;
}

// Embedding gather -> fp16 [B*S][E] (single precision term: per-step fresh
// tokens -> incoherent error ~5e-4, no lo needed)
__global__ void pack_xe_kernel(const int* __restrict__ x, const float* __restrict__ emb,
                               u16* __restrict__ xe) {
  int rs = blockIdx.x;
  int e = threadIdx.x;
  int idx = x[rs];
  xe[(size_t)rs * E_ + e] = f2h(emb[(size_t)idx * E_ + e]);
}

// ---------------------------------------------------------------------------
// Persistent dual-layer GRU kernel
// ---------------------------------------------------------------------------
__global__ void __launch_bounds__(256, 1)
gru_persistent(const u16* __restrict__ xe,
               const f16x8* __restrict__ wg0h, const f16x8* __restrict__ wg0l,
               const f16x8* __restrict__ wc0h, const f16x8* __restrict__ wc0l,
               const f16x8* __restrict__ wg1h, const f16x8* __restrict__ wg1l,
               const f16x8* __restrict__ wc1h, const f16x8* __restrict__ wc1l,
               const float* __restrict__ bg0, const float* __restrict__ bc0,
               const float* __restrict__ bg1, const float* __restrict__ bc1,
               const float* __restrict__ h00, const float* __restrict__ h01,
               u64* h0ph, u64* h0pl,   // parity x [32][1024] fp16 (2*8192 u64 each)
               u64* h1ph, u64* h1pl,
               u64* rh0h, u64* rh0l, u64* rh1h, u64* rh1l,
               u32* cnt, float* __restrict__ out) {
  extern __shared__ char smem[];
  char* A = smem;                               // fp16 [32][2048], stride 4096B, swizzled
  float* hM = (float*)(smem + 131072);          // fp32 [32][65] master h slice
  float* uB = (float*)(smem + 131072 + 8320);   // fp32 [32][65] u-gate slice
  u16* pS = (u16*)(smem + 131072 + 16640);      // [32][128]: cols 0..63 hi, 64..127 lo

  const int wg = blockIdx.x;
  const bool L1 = wg >= 16;
  const int w = L1 ? (wg - 16) : wg;
  const int tid = threadIdx.x;
  const int lane = tid & 63;
  const int wv = tid >> 6;
  const int lrow = lane & 15;
  const int kfb = (lane >> 4) << 4;
  const int lcol = wv * 16 + lrow;
  const int colg = w * 64 + lcol;
  const int rbase = (lane >> 4) << 2;

  // ---- init: load h slice, publish hi/lo (to parity buffer 1 for h0)
  const float* hsrc = L1 ? h01 : h00;
  u64* hpub_h = L1 ? h1ph : (h0ph + 8192);   // tau=0 reads parity (0+1)&1 = 1
  u64* hpub_l = L1 ? h1pl : (h0pl + 8192);
  for (int i = tid; i < 32 * 64; i += 256) {
    int r = i >> 6, c = i & 63;
    float v = hsrc[r * 1024 + w * 64 + c];
    hM[r * 65 + c] = v;
    u16 vh, vl; split16(v, vh, vl);
    pS[r * 128 + c] = vh;
    pS[r * 128 + 64 + c] = vl;
  }
  __syncthreads();
  for (int i = tid; i < 1024; i += 256) {
    int sel = i >> 9, j = i & 511;
    int r = j >> 4, c = j & 15;
    u64 v = *(const u64*)(pS + r * 128 + sel * 64 + c * 4);
    astore((sel ? hpub_l : hpub_h) + r * 256 + w * 16 + c, v);
  }
  unsigned tgt = NWG;
  gbar(cnt, tgt);

  const char* A0 = A + lrow * 4096;
  const char* A1 = A + (lrow + 16) * 4096;
  const int xr = SWZ_X(lrow);  // (lrow+16)&7 == lrow&7

  const int KC = L1 ? 64 : 40;   // K/32 per pass
  const int kc0 = L1 ? 0 : 8;    // lo-pass skips xe range (L0: k<256 has no lo)
  const f32x4 z = {0.f, 0.f, 0.f, 0.f};

  for (int tau = 0; tau <= S_; ++tau) {
    const int t = L1 ? (tau - 1) : tau;
    const bool act = (t >= 0) && (t < S_);
    const u64* h0h_pv = h0ph + (size_t)((tau + 1) & 1) * 8192;  // h0 from end of round tau-1
    const u64* h0l_pv = h0pl + (size_t)((tau + 1) & 1) * 8192;
    u64* h0h_cur = h0ph + (size_t)(tau & 1) * 8192;
    u64* h0l_cur = h0pl + (size_t)(tau & 1) * 8192;

    // ================= PHASE A: gates =================
    if (act) {
      // ---- stage hi operands
      if (!L1) {
        for (int i = tid; i < 1024; i += 256) {  // xe_t -> k[0,256)
          int r = i >> 5, c = i & 31;
          ulonglong2 v = *(const ulonglong2*)((const char*)xe + (size_t)(r * S_ + t) * 512 + c * 16);
          *(ulonglong2*)(A + ((r * 4096 + c * 16) ^ SWZ_X(r))) = v;
        }
        stage_pub(A, h0h_pv, 512, tid);          // h0 hi -> k[256,1280)
      } else {
        stage_pub(A, h0h_pv, 0, tid);            // y0 hi -> k[0,1024)
        stage_pub(A, h1ph, 2048, tid);           // h1 hi -> k[1024,2048)
      }
      __syncthreads();

      const f16x8* Wh = L1 ? wg1h : wg0h;
      const f16x8* Wl = L1 ? wg1l : wg0l;
      const int ntr = w * 4 + wv, ntu = 64 + ntr;
      const f16x8* bh_r = Wh + (size_t)ntr * KC * 64 + lane;
      const f16x8* bh_u = Wh + (size_t)ntu * KC * 64 + lane;
      const f16x8* bl_r = Wl + (size_t)ntr * KC * 64 + lane;
      const f16x8* bl_u = Wl + (size_t)ntu * KC * 64 + lane;
      f32x4 rh0a = z, rh1a = z, uh0a = z, uh1a = z;  // hi accums
      f32x4 rm0a = z, rm1a = z, um0a = z, um1a = z;  // mid accums (x 2^12)
#pragma unroll 2
      for (int kc = 0; kc < KC; ++kc) {  // pass 1+2: Whi*Ahi, Wlo'*Ahi
        f16x8 wbr = bh_r[kc * 64], wbu = bh_u[kc * 64];
        f16x8 vbr = bl_r[kc * 64], vbu = bl_u[kc * 64];
        int kb = (kc * 64 + kfb) ^ xr;
        f16x8 a0 = *(const f16x8*)(A0 + kb);
        f16x8 a1 = *(const f16x8*)(A1 + kb);
        rh0a = MFMA(a0, wbr, rh0a); rh1a = MFMA(a1, wbr, rh1a);
        uh0a = MFMA(a0, wbu, uh0a); uh1a = MFMA(a1, wbu, uh1a);
        rm0a = MFMA(a0, vbr, rm0a); rm1a = MFMA(a1, vbr, rm1a);
        um0a = MFMA(a0, vbu, um0a); um1a = MFMA(a1, vbu, um1a);
      }
      __syncthreads();  // all waves done reading hi A-tile

      // ---- stage lo' operands (overwrite act region)
      if (!L1) {
        stage_pub(A, h0l_pv, 512, tid);
      } else {
        stage_pub(A, h0l_pv, 0, tid);
        stage_pub(A, h1pl, 2048, tid);
      }
      __syncthreads();
#pragma unroll 2
      for (int kc = kc0; kc < KC; ++kc) {  // pass 3: Whi*Alo'
        f16x8 wbr = bh_r[kc * 64], wbu = bh_u[kc * 64];
        int kb = (kc * 64 + kfb) ^ xr;
        f16x8 a0 = *(const f16x8*)(A0 + kb);
        f16x8 a1 = *(const f16x8*)(A1 + kb);
        rm0a = MFMA(a0, wbr, rm0a); rm1a = MFMA(a1, wbr, rm1a);
        um0a = MFMA(a0, wbu, um0a); um1a = MFMA(a1, wbu, um1a);
      }

      const float* bg = L1 ? bg1 : bg0;
      const float bgr = bg[colg];
      const float bgu = bg[1024 + colg];
#pragma unroll
      for (int mt = 0; mt < 2; ++mt) {
        f32x4 gh_r = mt ? rh1a : rh0a, gm_r = mt ? rm1a : rm0a;
        f32x4 gh_u = mt ? uh1a : uh0a, gm_u = mt ? um1a : um0a;
#pragma unroll
        for (int i = 0; i < 4; ++i) {
          int row = mt * 16 + rbase + i;
          float r_ = sigm(gh_r[i] + gm_r[i] * LO_INV + bgr);
          float u_ = sigm(gh_u[i] + gm_u[i] * LO_INV + bgu);
          uB[row * 65 + lcol] = u_;
          float v = r_ * hM[row * 65 + lcol];
          u16 vh, vl; split16(v, vh, vl);
          pS[row * 128 + lcol] = vh;
          pS[row * 128 + 64 + lcol] = vl;
        }
      }
      __syncthreads();
      u64* rph = L1 ? rh1h : rh0h;
      u64* rpl = L1 ? rh1l : rh0l;
      for (int i = tid; i < 1024; i += 256) {
        int sel = i >> 9, j = i & 511;
        int r = j >> 4, c = j & 15;
        u64 v = *(const u64*)(pS + r * 128 + sel * 64 + c * 4);
        astore((sel ? rpl : rph) + r * 256 + w * 16 + c, v);
      }
    }
    gbar(cnt, tgt);

    // ================= PHASE B: candidate + h update =================
    if (act) {
      // ---- stage hi (L0: xe-hi intact at k[0,256); L1: restage y0 from
      //      parity buffer pv — L0 is concurrently writing cur, no race)
      if (!L1) {
        stage_pub(A, rh0h, 512, tid);
      } else {
        stage_pub(A, h0h_pv, 0, tid);
        stage_pub(A, rh1h, 2048, tid);
      }
      __syncthreads();

      const f16x8* Wh = L1 ? wc1h : wc0h;
      const f16x8* Wl = L1 ? wc1l : wc0l;
      const int ntc = w * 4 + wv;
      const f16x8* bh_c = Wh + (size_t)ntc * KC * 64 + lane;
      const f16x8* bl_c = Wl + (size_t)ntc * KC * 64 + lane;
      f32x4 ch0 = z, ch1 = z, cm0 = z, cm1 = z;
#pragma unroll 2
      for (int kc = 0; kc < KC; ++kc) {  // Whi*Ahi, Wlo'*Ahi
        f16x8 wb = bh_c[kc * 64];
        f16x8 vb = bl_c[kc * 64];
        int kb = (kc * 64 + kfb) ^ xr;
        f16x8 a0 = *(const f16x8*)(A0 + kb);
        f16x8 a1 = *(const f16x8*)(A1 + kb);
        ch0 = MFMA(a0, wb, ch0); ch1 = MFMA(a1, wb, ch1);
        cm0 = MFMA(a0, vb, cm0); cm1 = MFMA(a1, vb, cm1);
      }
      __syncthreads();
      if (!L1) {
        stage_pub(A, rh0l, 512, tid);
      } else {
        stage_pub(A, h0l_pv, 0, tid);
        stage_pub(A, rh1l, 2048, tid);
      }
      __syncthreads();
#pragma unroll 2
      for (int kc = kc0; kc < KC; ++kc) {  // Whi*Alo'
        f16x8 wb = bh_c[kc * 64];
        int kb = (kc * 64 + kfb) ^ xr;
        f16x8 a0 = *(const f16x8*)(A0 + kb);
        f16x8 a1 = *(const f16x8*)(A1 + kb);
        cm0 = MFMA(a0, wb, cm0); cm1 = MFMA(a1, wb, cm1);
      }

      const float* bc = L1 ? bc1 : bc0;
      const float bcv = bc[colg];
#pragma unroll
      for (int mt = 0; mt < 2; ++mt) {
        f32x4 ch = mt ? ch1 : ch0;
        f32x4 cm = mt ? cm1 : cm0;
#pragma unroll
        for (int i = 0; i < 4; ++i) {
          int row = mt * 16 + rbase + i;
          float cv = tanhf(ch[i] + cm[i] * LO_INV + bcv);
          float u_ = uB[row * 65 + lcol];
          float hm = hM[row * 65 + lcol];
          float hn = u_ * hm + (1.f - u_) * cv;
          hM[row * 65 + lcol] = hn;
          u16 vh, vl; split16(hn, vh, vl);
          pS[row * 128 + lcol] = vh;
          pS[row * 128 + 64 + lcol] = vl;
          if (L1) {
            out[(size_t)row * S_ * U_ + (size_t)t * U_ + colg] = hn;  // y1
            if (t == S_ - 1) out[(size_t)B_ * S_ * U_ + B_ * U_ + row * U_ + colg] = hn;  // s1
          } else {
            if (t == S_ - 1) out[(size_t)B_ * S_ * U_ + row * U_ + colg] = hn;            // s0
          }
        }
      }
      __syncthreads();
      u64* hph = L1 ? h1ph : h0h_cur;
      u64* hpl = L1 ? h1pl : h0l_cur;
      for (int i = tid; i < 1024; i += 256) {
        int sel = i >> 9, j = i & 511;
        int r = j >> 4, c = j & 15;
        u64 v = *(const u64*)(pS + r * 128 + sel * 64 + c * 4);
        astore((sel ? hpl : hph) + r * 256 + w * 16 + c, v);
      }
    }
    gbar(cnt, tgt);
  }
}

// ---------------------------------------------------------------------------
extern "C" void kernel_launch(void* const* d_in, const int* in_sizes, int n_in,
                              void* d_out, int out_size, void* d_ws, size_t ws_size,
                              hipStream_t stream) {
  const int* x = (const int*)d_in[0];
  const float* h00 = (const float*)d_in[1];
  const float* h01 = (const float*)d_in[2];
  const float* emb = (const float*)d_in[3];
  const float* Wg0 = (const float*)d_in[4];
  const float* bg0 = (const float*)d_in[5];
  const float* Wc0 = (const float*)d_in[6];
  const float* bc0 = (const float*)d_in[7];
  const float* Wg1 = (const float*)d_in[8];
  const float* bg1 = (const float*)d_in[9];
  const float* Wc1 = (const float*)d_in[10];
  const float* bc1 = (const float*)d_in[11];
  float* out = (float*)d_out;
  char* ws = (char*)d_ws;

  constexpr size_t WG0H = 0;                                    // 5120 frags
  constexpr size_t WG0L = WG0H + (size_t)5120 * 1024;
  constexpr size_t WC0H = WG0L + (size_t)5120 * 1024;           // 2560
  constexpr size_t WC0L = WC0H + (size_t)2560 * 1024;
  constexpr size_t WG1H = WC0L + (size_t)2560 * 1024;           // 8192
  constexpr size_t WG1L = WG1H + (size_t)8192 * 1024;
  constexpr size_t WC1H = WG1L + (size_t)8192 * 1024;           // 4096
  constexpr size_t WC1L = WC1H + (size_t)4096 * 1024;
  constexpr size_t XEO  = WC1L + (size_t)4096 * 1024;           // fp16 [B*S][E]
  constexpr size_t H0PH = XEO + (size_t)B_ * S_ * E_ * 2;       // 2 x 64KB (parity)
  constexpr size_t H0PL = H0PH + 131072;
  constexpr size_t H1PH = H0PL + 131072;                        // 64KB each
  constexpr size_t H1PL = H1PH + 65536;
  constexpr size_t RH0H = H1PL + 65536;
  constexpr size_t RH0L = RH0H + 65536;
  constexpr size_t RH1H = RH0L + 65536;
  constexpr size_t RH1L = RH1H + 65536;
  constexpr size_t CNT  = RH1L + 65536;
  constexpr size_t NEED = CNT + 128;
  if (ws_size < NEED) return;  // ~49.9 MB required

  (void)hipFuncSetAttribute((const void*)gru_persistent,
                            hipFuncAttributeMaxDynamicSharedMemorySize, LDS_BYTES);

  init_ws_kernel<<<1, 64, 0, stream>>>((u32*)(ws + CNT));
  pack_w_kernel<<<1280, 256, 0, stream>>>(Wg0, (u64*)(ws + WG0H), (u64*)(ws + WG0L), 1280, 2048);
  pack_w_kernel<<<640, 256, 0, stream>>>(Wc0, (u64*)(ws + WC0H), (u64*)(ws + WC0L), 1280, 1024);
  pack_w_kernel<<<2048, 256, 0, stream>>>(Wg1, (u64*)(ws + WG1H), (u64*)(ws + WG1L), 2048, 2048);
  pack_w_kernel<<<1024, 256, 0, stream>>>(Wc1, (u64*)(ws + WC1H), (u64*)(ws + WC1L), 2048, 1024);
  pack_xe_kernel<<<B_ * S_, E_, 0, stream>>>(x, emb, (u16*)(ws + XEO));

  gru_persistent<<<NWG, 256, LDS_BYTES, stream>>>(
      (const u16*)(ws + XEO),
      (const f16x8*)(ws + WG0H), (const f16x8*)(ws + WG0L),
      (const f16x8*)(ws + WC0H), (const f16x8*)(ws + WC0L),
      (const f16x8*)(ws + WG1H), (const f16x8*)(ws + WG1L),
      (const f16x8*)(ws + WC1H), (const f16x8*)(ws + WC1L),
      bg0, bc0, bg1, bc1, h00, h01,
      (u64*)(ws + H0PH), (u64*)(ws + H0PL),
      (u64*)(ws + H1PH), (u64*)(ws + H1PL),
      (u64*)(ws + RH0H), (u64*)(ws + RH0L),
      (u64*)(ws + RH1H), (u64*)(ws + RH1L),
      (u32*)(ws + CNT), out);
}

// Round 4
// 18080.153 us; speedup vs baseline: 2.2203x; 2.2203x over previous
//
#include <hip/hip_runtime.h>

// ============================================================================
// 2-layer GRU encoder (TF GRUCell), B=32, S=512, V=32000, E=256, U=1024.
//
// Round-3 kernel passed (absmax 0.0137, 40.2ms) but profile showed: 32 WGs,
// occupancy 1.56%, 11.2GB HBM/dispatch = weights re-streamed every round,
// latency-bound at 78us/round. This round: full-chip decomposition.
//
//  * 256 WGs = 2 layers x 16 colblocks(64 cols) x 8 K-slices. Per-WG weight
//    slice (~160KB) lives in VGPRs (192/wave) for ALL 512 steps -> weight
//    HBM traffic ~40MB once (was 10.6GB).
//  * Split-fp16 numerics preserved exactly (hi + 2^-12-scaled lo, fp32 acc):
//    same math as the passing kernel.
//  * K-partials combined via fp32 atomicAdd into LLC accumulators
//    acc_g[parity][l][w] (32x128: r|u) and acc_c (32x64). Parity double-
//    buffered; slices zero the other parity each round.
//  * NO publish arrays: each WG keeps an fp32 REPLICA of the h-columns its
//    K-slice consumes (L0: 128 h0-cols; L1 s<4: 256 y0-cols; L1 s>=4: 256
//    h1-cols), updates it each round from u/c accumulators (deterministic
//    fp32 -> all replicas bitwise-consistent), stages A-slice (split16) from
//    it, and reconstructs r*h from r-accumulators + replica. 2 global
//    barriers/round (8-group tree barrier).
//  * Outputs written by h1-replica holders (w==0): y1[:,tau-2] each round;
//    s0/s1 at the end. Loop tau=0..513 (L1 lags L0 by 1; +1 drain round).
// ============================================================================

#define B_ 32
#define S_ 512
#define E_ 256
#define U_ 1024
#define NWG 256
#define LO_SCALE 4096.f
#define LO_INV 2.44140625e-4f
#define LDS_BYTES 68608  // Ahi 16K + Alo 16K + hrep 32K + biases 3K

typedef unsigned long long u64;
typedef unsigned short u16;
typedef unsigned int u32;
typedef _Float16 f16x8 __attribute__((ext_vector_type(8)));
typedef float f32x4 __attribute__((ext_vector_type(4)));

#define MFMA(a, b, c) __builtin_amdgcn_mfma_f32_16x16x32_f16(a, b, c, 0, 0, 0)
#define SWZ_X(r) (((r) & 7) << 4)

union H16 { _Float16 h; u16 u; };

__device__ __forceinline__ u16 f2h(float f) { H16 c; c.h = (_Float16)f; return c.u; }
__device__ __forceinline__ void split16(float v, u16& hi, u16& lo) {
  H16 a; a.h = (_Float16)v; hi = a.u;
  H16 b; b.h = (_Float16)((v - (float)a.h) * LO_SCALE); lo = b.u;
}
__device__ __forceinline__ float sigm(float x) { return 1.f / (1.f + expf(-x)); }

__device__ __forceinline__ float aloadf(const float* p) {
  return __hip_atomic_load((float*)p, __ATOMIC_RELAXED, __HIP_MEMORY_SCOPE_AGENT);
}
__device__ __forceinline__ void astoref(float* p, float v) {
  __hip_atomic_store(p, v, __ATOMIC_RELAXED, __HIP_MEMORY_SCOPE_AGENT);
}

// 2-level tree barrier: 8 groups of 32 WGs; grp counters at cnt[gid*16],
// root at cnt[128]. bk = monotonic invocation count (same for all WGs).
__device__ __forceinline__ void gbar(u32* cnt, int gid, unsigned bk) {
  __syncthreads();  // drains vmcnt: all prior stores/atomics complete
  if (threadIdx.x == 0) {
    u32 v = __hip_atomic_fetch_add(cnt + gid * 16, 1u, __ATOMIC_RELEASE,
                                   __HIP_MEMORY_SCOPE_AGENT);
    if (v == bk * 32u - 1u)
      __hip_atomic_fetch_add(cnt + 128, 1u, __ATOMIC_RELEASE,
                             __HIP_MEMORY_SCOPE_AGENT);
    while (__hip_atomic_load(cnt + 128, __ATOMIC_RELAXED,
                             __HIP_MEMORY_SCOPE_AGENT) < bk * 8u) {}
  }
  __syncthreads();
  __atomic_signal_fence(__ATOMIC_ACQUIRE);
}

// ---------------------------------------------------------------------------
// Prep kernels
// ---------------------------------------------------------------------------
__global__ void init_cnt_kernel(u32* cnt) {
  cnt[threadIdx.x] = 0;  // 256 u32 = groups + root
}

// Gate weights: src fp32 [K][N] (N=2048). Frag id -> (w,s,wv,g,hl,kc);
// lane supplies B[k0+j][col], j=0..7 (B-operand of mfma_f32_16x16x32_f16).
__global__ void pack_gw(const float* __restrict__ src, u64* __restrict__ dst,
                        int KC, int N, int l1, int total) {
  int fid = blockIdx.x * 4 + (threadIdx.x >> 6);
  if (fid >= total) return;
  int lane = threadIdx.x & 63;
  int kc = fid % KC; int r1 = fid / KC;
  int hl = r1 & 1, g = (r1 >> 1) & 1; int blk = r1 >> 2;
  int wv = blk & 3, s = (blk >> 2) & 7, w = blk >> 5;
  int kcg = l1 ? (s * 8 + kc) : (kc == 0 ? s : 8 + s * 4 + (kc - 1));
  int col = g * (N >> 1) + w * 64 + wv * 16 + (lane & 15);
  int k0 = kcg * 32 + ((lane >> 4) << 3);
  u64 q0 = 0, q1 = 0;
#pragma unroll
  for (int j = 0; j < 4; ++j) {
    float v = src[(size_t)(k0 + j) * N + col];
    u16 h, lo; split16(v, h, lo);
    q0 |= (u64)(hl ? lo : h) << (16 * j);
  }
#pragma unroll
  for (int j = 0; j < 4; ++j) {
    float v = src[(size_t)(k0 + 4 + j) * N + col];
    u16 h, lo; split16(v, h, lo);
    q1 |= (u64)(hl ? lo : h) << (16 * j);
  }
  size_t o = ((size_t)fid * 64 + lane) * 2;
  dst[o] = q0; dst[o + 1] = q1;
}

// Candidate weights: src fp32 [K][1024].
__global__ void pack_cw(const float* __restrict__ src, u64* __restrict__ dst,
                        int KC, int l1, int total) {
  int fid = blockIdx.x * 4 + (threadIdx.x >> 6);
  if (fid >= total) return;
  int lane = threadIdx.x & 63;
  int kc = fid % KC; int r1 = fid / KC;
  int hl = r1 & 1; int blk = r1 >> 1;
  int wv = blk & 3, s = (blk >> 2) & 7, w = blk >> 5;
  int kcg = l1 ? (s * 8 + kc) : (kc == 0 ? s : 8 + s * 4 + (kc - 1));
  int col = w * 64 + wv * 16 + (lane & 15);
  int k0 = kcg * 32 + ((lane >> 4) << 3);
  u64 q0 = 0, q1 = 0;
#pragma unroll
  for (int j = 0; j < 4; ++j) {
    float v = src[(size_t)(k0 + j) * 1024 + col];
    u16 h, lo; split16(v, h, lo);
    q0 |= (u64)(hl ? lo : h) << (16 * j);
  }
#pragma unroll
  for (int j = 0; j < 4; ++j) {
    float v = src[(size_t)(k0 + 4 + j) * 1024 + col];
    u16 h, lo; split16(v, h, lo);
    q1 |= (u64)(hl ? lo : h) << (16 * j);
  }
  size_t o = ((size_t)fid * 64 + lane) * 2;
  dst[o] = q0; dst[o + 1] = q1;
}

// Embedding gather -> fp16 [B*S][E] (single fp16: fresh tokens each step ->
// incoherent error; validated by the passing round-3 kernel)
__global__ void pack_xe_kernel(const int* __restrict__ x, const float* __restrict__ emb,
                               u16* __restrict__ xe) {
  int rs = blockIdx.x;
  int e = threadIdx.x;
  int idx = x[rs];
  xe[(size_t)rs * E_ + e] = f2h(emb[(size_t)idx * E_ + e]);
}

// ---------------------------------------------------------------------------
// Persistent kernel: 256 WGs x 256 thr, weights in VGPRs
// ---------------------------------------------------------------------------
__global__ void __launch_bounds__(256, 1)
gru_persistent(const u16* __restrict__ xe,
               const f16x8* __restrict__ gw0, const f16x8* __restrict__ gw1,
               const f16x8* __restrict__ cw0, const f16x8* __restrict__ cw1,
               const float* __restrict__ bg0, const float* __restrict__ bc0,
               const float* __restrict__ bg1, const float* __restrict__ bc1,
               const float* __restrict__ h00, const float* __restrict__ h01,
               float* accg, float* accc, u32* cnt, float* __restrict__ out) {
  extern __shared__ char smem[];
  char* ABh = smem;                         // A-slice hi: [32 rows][512B], swizzled
  char* ABl = smem + 16384;                 // A-slice lo
  float* hrep = (float*)(smem + 32768);     // fp32 replica [32][ncr]
  float* bgrR = (float*)(smem + 65536);     // r-bias for replica cols
  float* bguR = bgrR + 256;                 // u-bias
  float* bcR  = bgrR + 512;                 // c-bias

  const int bid = blockIdx.x;
  const int l = bid >> 7;                   // layer
  const int w = (bid >> 3) & 15;            // colblock (64 cols)
  const int s = bid & 7;                    // K-slice
  const int gid = bid >> 5;                 // barrier group
  const int tid = threadIdx.x;
  const int lane = tid & 63;
  const int wv = tid >> 6;
  const int lrow = lane & 15;
  const int kfb = (lane >> 4) << 4;
  const int rbase = (lane >> 4) << 2;
  const int xr = SWZ_X(lrow);
  const int KCg = l ? 8 : 5;
  const bool repL1 = (l == 1 && s >= 4);    // replica holds h1 (else h0/y0)
  const int lr = repL1 ? 1 : 0;
  const int ncr = l ? 256 : 128;            // replica col count
  const int ncs = l ? 8 : 7;
  const int cb0 = l ? (repL1 ? 4 * (s - 4) : 4 * s) : 2 * s;
  const int rc0 = cb0 * 64;                 // replica col0 (within lr's U)
  const size_t OS0 = (size_t)B_ * S_ * U_;
  const size_t OS1 = OS0 + (size_t)B_ * U_;

  // ---- weights -> VGPRs (held across the whole sequence)
  const f16x8* GW = l ? gw1 : gw0;
  const f16x8* CW = l ? cw1 : cw0;
  const int blk = (w * 8 + s) * 4 + wv;
  f16x8 wrh[8], wrl[8], wuh[8], wul[8], wch[8], wcl[8];
#pragma unroll
  for (int kc = 0; kc < 8; ++kc) if (kc < KCg) {
    wrh[kc] = GW[((size_t)(blk * 4 + 0) * KCg + kc) * 64 + lane];
    wrl[kc] = GW[((size_t)(blk * 4 + 1) * KCg + kc) * 64 + lane];
    wuh[kc] = GW[((size_t)(blk * 4 + 2) * KCg + kc) * 64 + lane];
    wul[kc] = GW[((size_t)(blk * 4 + 3) * KCg + kc) * 64 + lane];
    wch[kc] = CW[((size_t)(blk * 2 + 0) * KCg + kc) * 64 + lane];
    wcl[kc] = CW[((size_t)(blk * 2 + 1) * KCg + kc) * 64 + lane];
  }

  // ---- init: replica, biases, zero accumulators
  {
    const float* hsrc = lr ? h01 : h00;
    for (int i = tid; i < 32 * ncr; i += 256) {
      int r = i >> ncs, c = i & (ncr - 1);
      hrep[i] = hsrc[r * 1024 + rc0 + c];
    }
    const float* bgL = lr ? bg1 : bg0;
    const float* bcL = lr ? bc1 : bc0;
    for (int i = tid; i < ncr; i += 256) {
      bgrR[i] = bgL[rc0 + i];
      bguR[i] = bgL[1024 + rc0 + i];
      bcR[i] = bcL[rc0 + i];
    }
#pragma unroll
    for (int j = 0; j < 6; ++j) {  // 393216 floats = 256 WG * 1536
      int idx = bid * 1536 + j * 256 + tid;
      if (idx < 262144) astoref(accg + idx, 0.f);
      else astoref(accc + (idx - 262144), 0.f);
    }
  }
  unsigned bk = 1;
  gbar(cnt, gid, bk);

  const char* Ah0 = ABh + lrow * 512;
  const char* Ah1 = ABh + (lrow + 16) * 512;
  const char* Al0 = ABl + lrow * 512;
  const char* Al1 = ABl + (lrow + 16) * 512;
  const f32x4 z = {0.f, 0.f, 0.f, 0.f};

  for (int tau = 0; tau <= 513; ++tau) {
    const int p = tau & 1;
    const bool act = l ? (tau >= 1 && tau <= 512) : (tau <= 511);

    // ============ G section: replica update, out, stage, gate MFMA ==========
    {
      const bool updOK = repL1 ? (tau >= 2) : (tau >= 1 && tau <= 512);
      if (updOK) {
        const float* agp = accg + ((size_t)((p ^ 1) * 2 + lr) * 16) * 4096;
        const float* acp = accc + ((size_t)((p ^ 1) * 2 + lr) * 16) * 2048;
        for (int i = tid; i < 32 * ncr; i += 256) {
          int r = i >> ncs, c = i & (ncr - 1);
          int cb = cb0 + (c >> 6), cc = c & 63;
          float uv = aloadf(agp + cb * 4096 + r * 128 + 64 + cc);
          float cv = aloadf(acp + cb * 2048 + r * 64 + cc);
          float u_ = sigm(uv + bguR[c]);
          float c_ = tanhf(cv + bcR[c]);
          hrep[i] = u_ * hrep[i] + (1.f - u_) * c_;
        }
      }
      __syncthreads();  // hrep ready

      // outputs (h1-replica holders w==0 write y1; L0 w==0 writes s0)
      if (repL1 && w == 0 && tau >= 2) {
        int t = tau - 2;
        for (int i = tid; i < 2048; i += 256) {
          int r = i >> 6, c4 = (i & 63) << 2;
          *(float4*)(out + (size_t)r * S_ * U_ + (size_t)t * U_ + rc0 + c4) =
              *(const float4*)(hrep + r * 256 + c4);
        }
        if (tau == 513) {
          for (int i = tid; i < 2048; i += 256) {
            int r = i >> 6, c4 = (i & 63) << 2;
            *(float4*)(out + OS1 + (size_t)r * U_ + rc0 + c4) =
                *(const float4*)(hrep + r * 256 + c4);
          }
        }
      }
      if (l == 0 && w == 0 && tau == 512) {
        for (int i = tid; i < 1024; i += 256) {
          int r = i >> 5, c4 = (i & 31) << 2;
          *(float4*)(out + OS0 + (size_t)r * U_ + rc0 + c4) =
              *(const float4*)(hrep + r * 128 + c4);
        }
      }

      if (act) {  // stage gate A-slice from replica (+xe for L0)
        if (l == 0) {
          int t = tau;
          for (int i = tid; i < 128; i += 256) {  // xe kc0: 32 rows x 4 chunks
            int r = i >> 2, c = i & 3;
            ulonglong2 v = *(const ulonglong2*)(xe + (size_t)(r * S_ + t) * 256 + s * 32 + c * 8);
            *(ulonglong2*)(ABh + ((r * 512 + c * 16) ^ SWZ_X(r))) = v;
          }
          for (int i = tid; i < 32 * 64; i += 256) {  // h-part: 2 cols/iter
            int r = i >> 6, j = (i & 63) * 2;
            u16 h0, l0, h1, l1;
            split16(hrep[r * 128 + j], h0, l0);
            split16(hrep[r * 128 + j + 1], h1, l1);
            int ba = (r * 512 + 64 + j * 2) ^ SWZ_X(r);
            *(u32*)(ABh + ba) = (u32)h0 | ((u32)h1 << 16);
            *(u32*)(ABl + ba) = (u32)l0 | ((u32)l1 << 16);
          }
        } else {
          for (int i = tid; i < 32 * 128; i += 256) {
            int r = i >> 7, j = (i & 127) * 2;
            u16 h0, l0, h1, l1;
            split16(hrep[r * 256 + j], h0, l0);
            split16(hrep[r * 256 + j + 1], h1, l1);
            int ba = (r * 512 + j * 2) ^ SWZ_X(r);
            *(u32*)(ABh + ba) = (u32)h0 | ((u32)h1 << 16);
            *(u32*)(ABl + ba) = (u32)l0 | ((u32)l1 << 16);
          }
        }
      }
      __syncthreads();

      if (act) {  // gate MFMA + atomic partial adds
        f32x4 rh0 = z, rh1 = z, uh0 = z, uh1 = z;
        f32x4 rm0 = z, rm1 = z, um0 = z, um1 = z;
#pragma unroll
        for (int kc = 0; kc < 8; ++kc) if (kc < KCg) {
          int kb = (kc * 64 + kfb) ^ xr;
          f16x8 a0 = *(const f16x8*)(Ah0 + kb);
          f16x8 a1 = *(const f16x8*)(Ah1 + kb);
          rh0 = MFMA(a0, wrh[kc], rh0); rh1 = MFMA(a1, wrh[kc], rh1);
          uh0 = MFMA(a0, wuh[kc], uh0); uh1 = MFMA(a1, wuh[kc], uh1);
          rm0 = MFMA(a0, wrl[kc], rm0); rm1 = MFMA(a1, wrl[kc], rm1);
          um0 = MFMA(a0, wul[kc], um0); um1 = MFMA(a1, wul[kc], um1);
          if (!(l == 0 && kc == 0)) {   // xe kc has no lo-A
            f16x8 b0 = *(const f16x8*)(Al0 + kb);
            f16x8 b1 = *(const f16x8*)(Al1 + kb);
            rm0 = MFMA(b0, wrh[kc], rm0); rm1 = MFMA(b1, wrh[kc], rm1);
            um0 = MFMA(b0, wuh[kc], um0); um1 = MFMA(b1, wuh[kc], um1);
          }
        }
        float* ag = accg + ((size_t)(p * 2 + l) * 16 + w) * 4096;
        const int lc = wv * 16 + lrow;
#pragma unroll
        for (int mt = 0; mt < 2; ++mt) {
          f32x4 rh = mt ? rh1 : rh0, rm = mt ? rm1 : rm0;
          f32x4 uh = mt ? uh1 : uh0, um = mt ? um1 : um0;
#pragma unroll
          for (int i = 0; i < 4; ++i) {
            int row = mt * 16 + rbase + i;
            atomicAdd(ag + row * 128 + lc, rh[i] + rm[i] * LO_INV);
            atomicAdd(ag + row * 128 + 64 + lc, uh[i] + um[i] * LO_INV);
          }
        }
      }
    }
    ++bk; gbar(cnt, gid, bk);

    // ============ C section: rh transform, cand MFMA, zero other parity =====
    {
      if (act && !(l == 1 && s < 4)) {  // L1 s<4: A = y0 as-is, no transform
        const float* agr = accg + ((size_t)(p * 2 + l) * 16) * 4096;
        if (l == 0) {
          for (int i = tid; i < 32 * 64; i += 256) {
            int r = i >> 6, j = (i & 63) * 2;
            int cb = cb0 + (j >> 6);
            float rv0 = aloadf(agr + cb * 4096 + r * 128 + (j & 63));
            float rv1 = aloadf(agr + cb * 4096 + r * 128 + ((j + 1) & 63));
            float q0 = sigm(rv0 + bgrR[j]) * hrep[r * 128 + j];
            float q1 = sigm(rv1 + bgrR[j + 1]) * hrep[r * 128 + j + 1];
            u16 h0, l0, h1, l1; split16(q0, h0, l0); split16(q1, h1, l1);
            int ba = (r * 512 + 64 + j * 2) ^ SWZ_X(r);
            *(u32*)(ABh + ba) = (u32)h0 | ((u32)h1 << 16);
            *(u32*)(ABl + ba) = (u32)l0 | ((u32)l1 << 16);
          }
        } else {
          for (int i = tid; i < 32 * 128; i += 256) {
            int r = i >> 7, j = (i & 127) * 2;
            int cb = cb0 + (j >> 6);
            float rv0 = aloadf(agr + cb * 4096 + r * 128 + (j & 63));
            float rv1 = aloadf(agr + cb * 4096 + r * 128 + ((j + 1) & 63));
            float q0 = sigm(rv0 + bgrR[j]) * hrep[r * 256 + j];
            float q1 = sigm(rv1 + bgrR[j + 1]) * hrep[r * 256 + j + 1];
            u16 h0, l0, h1, l1; split16(q0, h0, l0); split16(q1, h1, l1);
            int ba = (r * 512 + j * 2) ^ SWZ_X(r);
            *(u32*)(ABh + ba) = (u32)h0 | ((u32)h1 << 16);
            *(u32*)(ABl + ba) = (u32)l0 | ((u32)l1 << 16);
          }
        }
      }
      __syncthreads();

      if (act) {
        f32x4 ch0 = z, ch1 = z, cm0 = z, cm1 = z;
#pragma unroll
        for (int kc = 0; kc < 8; ++kc) if (kc < KCg) {
          int kb = (kc * 64 + kfb) ^ xr;
          f16x8 a0 = *(const f16x8*)(Ah0 + kb);
          f16x8 a1 = *(const f16x8*)(Ah1 + kb);
          ch0 = MFMA(a0, wch[kc], ch0); ch1 = MFMA(a1, wch[kc], ch1);
          cm0 = MFMA(a0, wcl[kc], cm0); cm1 = MFMA(a1, wcl[kc], cm1);
          if (!(l == 0 && kc == 0)) {
            f16x8 b0 = *(const f16x8*)(Al0 + kb);
            f16x8 b1 = *(const f16x8*)(Al1 + kb);
            cm0 = MFMA(b0, wch[kc], cm0); cm1 = MFMA(b1, wch[kc], cm1);
          }
        }
        float* ac = accc + ((size_t)(p * 2 + l) * 16 + w) * 2048;
        const int lc = wv * 16 + lrow;
#pragma unroll
        for (int mt = 0; mt < 2; ++mt) {
          f32x4 ch = mt ? ch1 : ch0, cm = mt ? cm1 : cm0;
#pragma unroll
          for (int i = 0; i < 4; ++i) {
            int row = mt * 16 + rbase + i;
            atomicAdd(ac + row * 64 + lc, ch[i] + cm[i] * LO_INV);
          }
        }
      }

      // zero other-parity accumulators (read window closed at last barrier)
      float* zg = accg + ((size_t)((p ^ 1) * 2 + l) * 16 + w) * 4096 + s * 512;
      for (int i = tid; i < 512; i += 256) astoref(zg + i, 0.f);
      float* zc = accc + ((size_t)((p ^ 1) * 2 + l) * 16 + w) * 2048 + s * 256;
      astoref(zc + tid, 0.f);
    }
    ++bk; gbar(cnt, gid, bk);
  }
}

// ---------------------------------------------------------------------------
extern "C" void kernel_launch(void* const* d_in, const int* in_sizes, int n_in,
                              void* d_out, int out_size, void* d_ws, size_t ws_size,
                              hipStream_t stream) {
  const int* x = (const int*)d_in[0];
  const float* h00 = (const float*)d_in[1];
  const float* h01 = (const float*)d_in[2];
  const float* emb = (const float*)d_in[3];
  const float* Wg0 = (const float*)d_in[4];
  const float* bg0 = (const float*)d_in[5];
  const float* Wc0 = (const float*)d_in[6];
  const float* bc0 = (const float*)d_in[7];
  const float* Wg1 = (const float*)d_in[8];
  const float* bg1 = (const float*)d_in[9];
  const float* Wc1 = (const float*)d_in[10];
  const float* bc1 = (const float*)d_in[11];
  float* out = (float*)d_out;
  char* ws = (char*)d_ws;

  // frag counts: gates = 16w*8s*4wv*2g*2hl*KC ; cand = 16*8*4*2hl*KC
  constexpr int FG0 = 10240, FG1 = 16384, FC0 = 5120, FC1 = 8192;
  constexpr size_t GW0 = 0;
  constexpr size_t GW1 = GW0 + (size_t)FG0 * 1024;
  constexpr size_t CW0 = GW1 + (size_t)FG1 * 1024;
  constexpr size_t CW1 = CW0 + (size_t)FC0 * 1024;
  constexpr size_t XEO = CW1 + (size_t)FC1 * 1024;
  constexpr size_t ACG = XEO + (size_t)B_ * S_ * E_ * 2;   // 262144 fp32
  constexpr size_t ACC = ACG + 262144 * 4;                  // 131072 fp32
  constexpr size_t CNT = ACC + 131072 * 4;
  constexpr size_t NEED = CNT + 1024;
  if (ws_size < NEED) return;  // ~48.5 MB

  (void)hipFuncSetAttribute((const void*)gru_persistent,
                            hipFuncAttributeMaxDynamicSharedMemorySize, LDS_BYTES);

  init_cnt_kernel<<<1, 256, 0, stream>>>((u32*)(ws + CNT));
  pack_gw<<<FG0 / 4, 256, 0, stream>>>(Wg0, (u64*)(ws + GW0), 5, 2048, 0, FG0);
  pack_gw<<<FG1 / 4, 256, 0, stream>>>(Wg1, (u64*)(ws + GW1), 8, 2048, 1, FG1);
  pack_cw<<<FC0 / 4, 256, 0, stream>>>(Wc0, (u64*)(ws + CW0), 5, 0, FC0);
  pack_cw<<<FC1 / 4, 256, 0, stream>>>(Wc1, (u64*)(ws + CW1), 8, 1, FC1);
  pack_xe_kernel<<<B_ * S_, E_, 0, stream>>>(x, emb, (u16*)(ws + XEO));

  gru_persistent<<<NWG, 256, LDS_BYTES, stream>>>(
      (const u16*)(ws + XEO),
      (const f16x8*)(ws + GW0), (const f16x8*)(ws + GW1),
      (const f16x8*)(ws + CW0), (const f16x8*)(ws + CW1),
      bg0, bc0, bg1, bc1, h00, h01,
      (float*)(ws + ACG), (float*)(ws + ACC), (u32*)(ws + CNT), out);
}

// Round 5
// 13287.596 us; speedup vs baseline: 3.0211x; 1.3607x over previous
//
#include <hip/hip_runtime.h>

// ============================================================================
// 2-layer GRU encoder (TF GRUCell), B=32, S=512, V=32000, E=256, U=1024.
//
// Round-4 (passed, 17.7ms): 256 WGs, weights in VGPRs, K-sliced partials via
// LLC atomicAdd, fp32 replicas, 2 global tree barriers/round -> 34.5us/round
// with only ~6us of instructions: stall-dominated (barrier convoy + ~1us LLC
// hops + libm expf/tanhf redundant x8 + scalar acc reads).
//
// Round-5 changes (data flow & numerics identical to the passing kernel):
//  * NO global barriers: per-layer monotonic counters cnt_g[l], cnt_c[l]
//    (4 sub-words each to cut RMW contention). Each WG polls only what its
//    next read needs; layers decouple (L1 h1-slices never wait on L0).
//    Cross-layer WAR (L0 zeroing acc slots L1 replicas still read) gated by
//    cnt_g1 >= 32*tau. Parity-2 accs + prep-kernel zeroing make it safe.
//  * __expf-based sigmoid/tanh (deterministic, ~1ulp; replicas stay bitwise
//    consistent since all WGs use the same function).
//  * Acc reads batched as u64 pairs (issue 8-16 loads, then compute).
//  * Replica-update fused with A-tile staging (same (r,c2) mapping).
//  * Split-fp16 MFMA (hi + 2^-12 lo), fp32 accum/state: unchanged.
// ============================================================================

#define B_ 32
#define S_ 512
#define E_ 256
#define U_ 1024
#define NWG 256
#define LO_SCALE 4096.f
#define LO_INV 2.44140625e-4f
#define LDS_BYTES 68608  // ABh 16K + ABl 16K + hrep 32K + biases 3K

#define G0W 0
#define C0W 16
#define G1W 32
#define C1W 48

typedef unsigned long long u64;
typedef unsigned short u16;
typedef unsigned int u32;
typedef _Float16 f16x8 __attribute__((ext_vector_type(8)));
typedef float f32x4 __attribute__((ext_vector_type(4)));

#define MFMA(a, b, c) __builtin_amdgcn_mfma_f32_16x16x32_f16(a, b, c, 0, 0, 0)
#define SWZ_X(r) (((r) & 7) << 4)

union H16 { _Float16 h; u16 u; };
union PF { u64 q; float f[2]; };

__device__ __forceinline__ u16 f2h(float f) { H16 c; c.h = (_Float16)f; return c.u; }
__device__ __forceinline__ void split16(float v, u16& hi, u16& lo) {
  H16 a; a.h = (_Float16)v; hi = a.u;
  H16 b; b.h = (_Float16)((v - (float)a.h) * LO_SCALE); lo = b.u;
}
// __expf-based: deterministic (all replicas use same fn), ~1ulp accurate.
__device__ __forceinline__ float sigm(float x) { return 1.f / (1.f + __expf(-x)); }
__device__ __forceinline__ float tanh_(float x) { return 2.f / (1.f + __expf(-2.f * x)) - 1.f; }

__device__ __forceinline__ u64 aload64(const float* p) {
  return __hip_atomic_load((const u64*)p, __ATOMIC_RELAXED, __HIP_MEMORY_SCOPE_AGENT);
}
__device__ __forceinline__ void astoref(float* p, float v) {
  __hip_atomic_store(p, v, __ATOMIC_RELAXED, __HIP_MEMORY_SCOPE_AGENT);
}
__device__ __forceinline__ u32 aldu32(const u32* p) {
  return __hip_atomic_load(p, __ATOMIC_RELAXED, __HIP_MEMORY_SCOPE_AGENT);
}

// Wait until all 4 sub-words of a counter reach thr. WG-uniform call.
__device__ __forceinline__ void waitge(const u32* c, u32 thr) {
  if (threadIdx.x == 0 && thr) {
    while (aldu32(c) < thr || aldu32(c + 1) < thr ||
           aldu32(c + 2) < thr || aldu32(c + 3) < thr) {}
  }
  __syncthreads();
  __atomic_signal_fence(__ATOMIC_ACQUIRE);
}
__device__ __forceinline__ void bump(u32* c) {
  __hip_atomic_fetch_add(c, 1u, __ATOMIC_RELEASE, __HIP_MEMORY_SCOPE_AGENT);
}

// ---------------------------------------------------------------------------
// Prep kernels
// ---------------------------------------------------------------------------
__global__ void init_cnt_kernel(u32* cnt) {
  __hip_atomic_store(cnt + threadIdx.x, 0u, __ATOMIC_RELAXED, __HIP_MEMORY_SCOPE_AGENT);
}
__global__ void zero_acc_kernel(float* accg, float* accc) {
  int idx = blockIdx.x * 256 + threadIdx.x;
  if (idx < 262144) astoref(accg + idx, 0.f);
  else astoref(accc + (idx - 262144), 0.f);
}

// Gate weights: src fp32 [K][N] (N=2048) -> fragment-major fp16 hi/lo.
__global__ void pack_gw(const float* __restrict__ src, u64* __restrict__ dst,
                        int KC, int N, int l1, int total) {
  int fid = blockIdx.x * 4 + (threadIdx.x >> 6);
  if (fid >= total) return;
  int lane = threadIdx.x & 63;
  int kc = fid % KC; int r1 = fid / KC;
  int hl = r1 & 1, g = (r1 >> 1) & 1; int blk = r1 >> 2;
  int wv = blk & 3, s = (blk >> 2) & 7, w = blk >> 5;
  int kcg = l1 ? (s * 8 + kc) : (kc == 0 ? s : 8 + s * 4 + (kc - 1));
  int col = g * (N >> 1) + w * 64 + wv * 16 + (lane & 15);
  int k0 = kcg * 32 + ((lane >> 4) << 3);
  u64 q0 = 0, q1 = 0;
#pragma unroll
  for (int j = 0; j < 4; ++j) {
    float v = src[(size_t)(k0 + j) * N + col];
    u16 h, lo; split16(v, h, lo);
    q0 |= (u64)(hl ? lo : h) << (16 * j);
  }
#pragma unroll
  for (int j = 0; j < 4; ++j) {
    float v = src[(size_t)(k0 + 4 + j) * N + col];
    u16 h, lo; split16(v, h, lo);
    q1 |= (u64)(hl ? lo : h) << (16 * j);
  }
  size_t o = ((size_t)fid * 64 + lane) * 2;
  dst[o] = q0; dst[o + 1] = q1;
}

// Candidate weights: src fp32 [K][1024].
__global__ void pack_cw(const float* __restrict__ src, u64* __restrict__ dst,
                        int KC, int l1, int total) {
  int fid = blockIdx.x * 4 + (threadIdx.x >> 6);
  if (fid >= total) return;
  int lane = threadIdx.x & 63;
  int kc = fid % KC; int r1 = fid / KC;
  int hl = r1 & 1; int blk = r1 >> 1;
  int wv = blk & 3, s = (blk >> 2) & 7, w = blk >> 5;
  int kcg = l1 ? (s * 8 + kc) : (kc == 0 ? s : 8 + s * 4 + (kc - 1));
  int col = w * 64 + wv * 16 + (lane & 15);
  int k0 = kcg * 32 + ((lane >> 4) << 3);
  u64 q0 = 0, q1 = 0;
#pragma unroll
  for (int j = 0; j < 4; ++j) {
    float v = src[(size_t)(k0 + j) * 1024 + col];
    u16 h, lo; split16(v, h, lo);
    q0 |= (u64)(hl ? lo : h) << (16 * j);
  }
#pragma unroll
  for (int j = 0; j < 4; ++j) {
    float v = src[(size_t)(k0 + 4 + j) * 1024 + col];
    u16 h, lo; split16(v, h, lo);
    q1 |= (u64)(hl ? lo : h) << (16 * j);
  }
  size_t o = ((size_t)fid * 64 + lane) * 2;
  dst[o] = q0; dst[o + 1] = q1;
}

__global__ void pack_xe_kernel(const int* __restrict__ x, const float* __restrict__ emb,
                               u16* __restrict__ xe) {
  int rs = blockIdx.x;
  int e = threadIdx.x;
  int idx = x[rs];
  xe[(size_t)rs * E_ + e] = f2h(emb[(size_t)idx * E_ + e]);
}

// ---------------------------------------------------------------------------
// Persistent kernel: 256 WGs x 256 thr, weights in VGPRs, counter-sync
// ---------------------------------------------------------------------------
__global__ void __launch_bounds__(256, 1)
gru_persistent(const u16* __restrict__ xe,
               const f16x8* __restrict__ gw0, const f16x8* __restrict__ gw1,
               const f16x8* __restrict__ cw0, const f16x8* __restrict__ cw1,
               const float* __restrict__ bg0, const float* __restrict__ bc0,
               const float* __restrict__ bg1, const float* __restrict__ bc1,
               const float* __restrict__ h00, const float* __restrict__ h01,
               float* accg, float* accc, u32* cnt, float* __restrict__ out) {
  extern __shared__ char smem[];
  char* ABh = smem;                         // A-slice hi: [32 rows][512B], swizzled
  char* ABl = smem + 16384;                 // A-slice lo
  float* hrep = (float*)(smem + 32768);     // fp32 replica [32][ncr]
  float* bgrR = (float*)(smem + 65536);
  float* bguR = bgrR + 256;
  float* bcR  = bgrR + 512;

  const int bid = blockIdx.x;
  const int l = bid >> 7;                   // layer
  const int w = (bid >> 3) & 15;            // colblock (64 cols)
  const int s = bid & 7;                    // K-slice
  const int tid = threadIdx.x;
  const int lane = tid & 63;
  const int wv = tid >> 6;
  const int lrow = lane & 15;
  const int kfb = (lane >> 4) << 4;
  const int rbase = (lane >> 4) << 2;
  const int xr = SWZ_X(lrow);
  const int KCg = l ? 8 : 5;
  const bool repL1 = (l == 1 && s >= 4);
  const int lr = repL1 ? 1 : 0;
  const int ncs = l ? 8 : 7;                // log2(replica col count)
  const int cb0 = l ? (repL1 ? 4 * (s - 4) : 4 * s) : 2 * s;
  const int rc0 = cb0 * 64;
  const int prsh = ncs - 1;                 // log2(pairs per row)
  const int nb = l ? 2 : 1;                 // batches of 8 pairs per thread
  const size_t OS0 = (size_t)B_ * S_ * U_;
  const size_t OS1 = OS0 + (size_t)B_ * U_;

  // ---- weights -> VGPRs (held across the whole sequence)
  const f16x8* GW = l ? gw1 : gw0;
  const f16x8* CW = l ? cw1 : cw0;
  const int blk = (w * 8 + s) * 4 + wv;
  f16x8 wrh[8], wrl[8], wuh[8], wul[8], wch[8], wcl[8];
#pragma unroll
  for (int kc = 0; kc < 8; ++kc) if (kc < KCg) {
    wrh[kc] = GW[((size_t)(blk * 4 + 0) * KCg + kc) * 64 + lane];
    wrl[kc] = GW[((size_t)(blk * 4 + 1) * KCg + kc) * 64 + lane];
    wuh[kc] = GW[((size_t)(blk * 4 + 2) * KCg + kc) * 64 + lane];
    wul[kc] = GW[((size_t)(blk * 4 + 3) * KCg + kc) * 64 + lane];
    wch[kc] = CW[((size_t)(blk * 2 + 0) * KCg + kc) * 64 + lane];
    wcl[kc] = CW[((size_t)(blk * 2 + 1) * KCg + kc) * 64 + lane];
  }

  // ---- init replica + biases (accs zeroed by prep kernel)
  {
    const int ncr = 1 << ncs;
    const float* hsrc = lr ? h01 : h00;
    for (int i = tid; i < 32 * ncr; i += 256) {
      int r = i >> ncs, c = i & (ncr - 1);
      hrep[i] = hsrc[r * 1024 + rc0 + c];
    }
    const float* bgL = lr ? bg1 : bg0;
    const float* bcL = lr ? bc1 : bc0;
    for (int i = tid; i < ncr; i += 256) {
      bgrR[i] = bgL[rc0 + i];
      bguR[i] = bgL[1024 + rc0 + i];
      bcR[i] = bcL[rc0 + i];
    }
  }
  __syncthreads();

  const char* Ah0 = ABh + lrow * 512;
  const char* Ah1 = ABh + (lrow + 16) * 512;
  const char* Al0 = ABl + lrow * 512;
  const char* Al1 = ABl + (lrow + 16) * 512;
  const f32x4 z = {0.f, 0.f, 0.f, 0.f};
  const int hofs = l ? 0 : 64;              // byte col of h-region in A row

  for (int tau = (l ? 1 : 0); tau <= (l ? 513 : 512); ++tau) {
    const int p = tau & 1;
    const bool act = l ? (tau <= 512) : (tau <= 511);
    const bool updOK = l ? (repL1 ? (tau >= 2) : (tau <= 512)) : (tau >= 1);

    // ======== G: polls ========
    if (l == 0) {
      if (tau >= 1) waitge(cnt + C0W, 32u * (u32)tau);
    } else {
      waitge(cnt + C1W, 32u * (u32)(tau - 1));
      if (s < 4 && tau <= 512) waitge(cnt + C0W, 32u * (u32)tau);
    }

    // ======== replica update (fused with A-stage) / stage-only ========
    if (updOK) {
      const float* agp = accg + ((size_t)(((p ^ 1) * 2) + lr) * 16) * 4096;
      const float* acp = accc + ((size_t)(((p ^ 1) * 2) + lr) * 16) * 2048;
      for (int b = 0; b < nb; ++b) {
        u64 ub[8], cb8[8];
#pragma unroll
        for (int j = 0; j < 8; ++j) {
          int pi = (b * 8 + j) * 256 + tid;
          int r = pi >> prsh, c2 = (pi & ((1 << prsh) - 1)) * 2;
          int cb = cb0 + (c2 >> 6), cc = c2 & 63;
          ub[j] = aload64(agp + cb * 4096 + r * 128 + 64 + cc);
          cb8[j] = aload64(acp + cb * 2048 + r * 64 + cc);
        }
#pragma unroll
        for (int j = 0; j < 8; ++j) {
          int pi = (b * 8 + j) * 256 + tid;
          int r = pi >> prsh, c2 = (pi & ((1 << prsh) - 1)) * 2;
          PF uu, cv; uu.q = ub[j]; cv.q = cb8[j];
          float u0 = sigm(uu.f[0] + bguR[c2]);
          float u1 = sigm(uu.f[1] + bguR[c2 + 1]);
          float t0 = tanh_(cv.f[0] + bcR[c2]);
          float t1 = tanh_(cv.f[1] + bcR[c2 + 1]);
          int hb = (r << ncs) + c2;
          float n0 = u0 * hrep[hb] + (1.f - u0) * t0;
          float n1 = u1 * hrep[hb + 1] + (1.f - u1) * t1;
          hrep[hb] = n0; hrep[hb + 1] = n1;
          if (act) {
            u16 a0, b0, a1, b1; split16(n0, a0, b0); split16(n1, a1, b1);
            int ba = (r * 512 + hofs + c2 * 2) ^ SWZ_X(r);
            *(u32*)(ABh + ba) = (u32)a0 | ((u32)a1 << 16);
            *(u32*)(ABl + ba) = (u32)b0 | ((u32)b1 << 16);
          }
        }
      }
    } else if (act) {  // first rounds: stage initial hrep
      for (int b = 0; b < nb; ++b)
#pragma unroll
        for (int j = 0; j < 8; ++j) {
          int pi = (b * 8 + j) * 256 + tid;
          int r = pi >> prsh, c2 = (pi & ((1 << prsh) - 1)) * 2;
          int hb = (r << ncs) + c2;
          u16 a0, b0, a1, b1; split16(hrep[hb], a0, b0); split16(hrep[hb + 1], a1, b1);
          int ba = (r * 512 + hofs + c2 * 2) ^ SWZ_X(r);
          *(u32*)(ABh + ba) = (u32)a0 | ((u32)a1 << 16);
          *(u32*)(ABl + ba) = (u32)b0 | ((u32)b1 << 16);
        }
    }
    if (l == 0 && act) {  // xe_t -> A cols [0,32)
      for (int i = tid; i < 128; i += 256) {
        int r = i >> 2, c = i & 3;
        ulonglong2 v = *(const ulonglong2*)(xe + (size_t)(r * S_ + tau) * 256 + s * 32 + c * 8);
        *(ulonglong2*)(ABh + ((r * 512 + c * 16) ^ SWZ_X(r))) = v;
      }
    }
    __syncthreads();  // hrep + A-tile ready

    // ======== outputs (from hrep) ========
    if (repL1 && w == 0 && tau >= 2) {
      int t = tau - 2;
      for (int i = tid; i < 2048; i += 256) {
        int r = i >> 6, c4 = (i & 63) << 2;
        *(float4*)(out + (size_t)r * S_ * U_ + (size_t)t * U_ + rc0 + c4) =
            *(const float4*)(hrep + r * 256 + c4);
      }
      if (tau == 513) {
        for (int i = tid; i < 2048; i += 256) {
          int r = i >> 6, c4 = (i & 63) << 2;
          *(float4*)(out + OS1 + (size_t)r * U_ + rc0 + c4) =
              *(const float4*)(hrep + r * 256 + c4);
        }
      }
    }
    if (l == 0 && w == 0 && tau == 512) {
      for (int i = tid; i < 1024; i += 256) {
        int r = i >> 5, c4 = (i & 31) << 2;
        *(float4*)(out + OS0 + (size_t)r * U_ + rc0 + c4) =
            *(const float4*)(hrep + r * 128 + c4);
      }
    }

    // ======== gate MFMA + atomic partial adds ========
    if (act) {
      f32x4 rh0 = z, rh1 = z, uh0 = z, uh1 = z;
      f32x4 rm0 = z, rm1 = z, um0 = z, um1 = z;
#pragma unroll
      for (int kc = 0; kc < 8; ++kc) if (kc < KCg) {
        int kb = (kc * 64 + kfb) ^ xr;
        f16x8 a0 = *(const f16x8*)(Ah0 + kb);
        f16x8 a1 = *(const f16x8*)(Ah1 + kb);
        rh0 = MFMA(a0, wrh[kc], rh0); rh1 = MFMA(a1, wrh[kc], rh1);
        uh0 = MFMA(a0, wuh[kc], uh0); uh1 = MFMA(a1, wuh[kc], uh1);
        rm0 = MFMA(a0, wrl[kc], rm0); rm1 = MFMA(a1, wrl[kc], rm1);
        um0 = MFMA(a0, wul[kc], um0); um1 = MFMA(a1, wul[kc], um1);
        if (!(l == 0 && kc == 0)) {  // xe kc has no lo-A
          f16x8 b0 = *(const f16x8*)(Al0 + kb);
          f16x8 b1 = *(const f16x8*)(Al1 + kb);
          rm0 = MFMA(b0, wrh[kc], rm0); rm1 = MFMA(b1, wrh[kc], rm1);
          um0 = MFMA(b0, wuh[kc], um0); um1 = MFMA(b1, wuh[kc], um1);
        }
      }
      float* ag = accg + ((size_t)(p * 2 + l) * 16 + w) * 4096;
      const int lc = wv * 16 + lrow;
#pragma unroll
      for (int mt = 0; mt < 2; ++mt) {
        f32x4 rh = mt ? rh1 : rh0, rm = mt ? rm1 : rm0;
        f32x4 uh = mt ? uh1 : uh0, um = mt ? um1 : um0;
#pragma unroll
        for (int i = 0; i < 4; ++i) {
          int row = mt * 16 + rbase + i;
          atomicAdd(ag + row * 128 + lc, rh[i] + rm[i] * LO_INV);
          atomicAdd(ag + row * 128 + 64 + lc, uh[i] + um[i] * LO_INV);
        }
      }
    }
    __syncthreads();  // drain adds (all waves) before signaling
    if (act && tid == 0) bump(cnt + (l ? G1W : G0W) + (w & 3));

    // ======== C: rh transform, cand MFMA, zero other parity ========
    if (act) {
      waitge(cnt + G1W, 32u * (u32)tau);                  // cross/own-layer read gate
      if (l == 0) waitge(cnt + G0W, 32u * (u32)(tau + 1));  // own-layer adds+reads
      // zero other-parity stripes (readers proven done by the polls above)
      {
        float* zg = accg + ((size_t)(((p ^ 1) * 2) + l) * 16 + w) * 4096 + s * 512;
        for (int i = tid; i < 512; i += 256) astoref(zg + i, 0.f);
        float* zc = accc + ((size_t)(((p ^ 1) * 2) + l) * 16 + w) * 2048 + s * 256;
        astoref(zc + tid, 0.f);
      }
      if (!(l == 1 && s < 4)) {  // L1 s<4: A = y0 as-is
        const float* agr = accg + ((size_t)(p * 2 + l) * 16) * 4096;
        for (int b = 0; b < nb; ++b) {
          u64 rb[8];
#pragma unroll
          for (int j = 0; j < 8; ++j) {
            int pi = (b * 8 + j) * 256 + tid;
            int r = pi >> prsh, c2 = (pi & ((1 << prsh) - 1)) * 2;
            int cb = cb0 + (c2 >> 6), cc = c2 & 63;
            rb[j] = aload64(agr + cb * 4096 + r * 128 + cc);
          }
#pragma unroll
          for (int j = 0; j < 8; ++j) {
            int pi = (b * 8 + j) * 256 + tid;
            int r = pi >> prsh, c2 = (pi & ((1 << prsh) - 1)) * 2;
            int hb = (r << ncs) + c2;
            PF rv; rv.q = rb[j];
            float q0 = sigm(rv.f[0] + bgrR[c2]) * hrep[hb];
            float q1 = sigm(rv.f[1] + bgrR[c2 + 1]) * hrep[hb + 1];
            u16 a0, b0, a1, b1; split16(q0, a0, b0); split16(q1, a1, b1);
            int ba = (r * 512 + hofs + c2 * 2) ^ SWZ_X(r);
            *(u32*)(ABh + ba) = (u32)a0 | ((u32)a1 << 16);
            *(u32*)(ABl + ba) = (u32)b0 | ((u32)b1 << 16);
          }
        }
      }
      __syncthreads();

      f32x4 ch0 = z, ch1 = z, cm0 = z, cm1 = z;
#pragma unroll
      for (int kc = 0; kc < 8; ++kc) if (kc < KCg) {
        int kb = (kc * 64 + kfb) ^ xr;
        f16x8 a0 = *(const f16x8*)(Ah0 + kb);
        f16x8 a1 = *(const f16x8*)(Ah1 + kb);
        ch0 = MFMA(a0, wch[kc], ch0); ch1 = MFMA(a1, wch[kc], ch1);
        cm0 = MFMA(a0, wcl[kc], cm0); cm1 = MFMA(a1, wcl[kc], cm1);
        if (!(l == 0 && kc == 0)) {
          f16x8 b0 = *(const f16x8*)(Al0 + kb);
          f16x8 b1 = *(const f16x8*)(Al1 + kb);
          cm0 = MFMA(b0, wch[kc], cm0); cm1 = MFMA(b1, wch[kc], cm1);
        }
      }
      float* ac = accc + ((size_t)(p * 2 + l) * 16 + w) * 2048;
      const int lc = wv * 16 + lrow;
#pragma unroll
      for (int mt = 0; mt < 2; ++mt) {
        f32x4 ch = mt ? ch1 : ch0, cm = mt ? cm1 : cm0;
#pragma unroll
        for (int i = 0; i < 4; ++i) {
          int row = mt * 16 + rbase + i;
          atomicAdd(ac + row * 64 + lc, ch[i] + cm[i] * LO_INV);
        }
      }
      __syncthreads();  // drain adds + zero stores
      if (tid == 0) bump(cnt + (l ? C1W : C0W) + (w & 3));
    }
  }
}

// ---------------------------------------------------------------------------
extern "C" void kernel_launch(void* const* d_in, const int* in_sizes, int n_in,
                              void* d_out, int out_size, void* d_ws, size_t ws_size,
                              hipStream_t stream) {
  const int* x = (const int*)d_in[0];
  const float* h00 = (const float*)d_in[1];
  const float* h01 = (const float*)d_in[2];
  const float* emb = (const float*)d_in[3];
  const float* Wg0 = (const float*)d_in[4];
  const float* bg0 = (const float*)d_in[5];
  const float* Wc0 = (const float*)d_in[6];
  const float* bc0 = (const float*)d_in[7];
  const float* Wg1 = (const float*)d_in[8];
  const float* bg1 = (const float*)d_in[9];
  const float* Wc1 = (const float*)d_in[10];
  const float* bc1 = (const float*)d_in[11];
  float* out = (float*)d_out;
  char* ws = (char*)d_ws;

  constexpr int FG0 = 10240, FG1 = 16384, FC0 = 5120, FC1 = 8192;
  constexpr size_t GW0 = 0;
  constexpr size_t GW1 = GW0 + (size_t)FG0 * 1024;
  constexpr size_t CW0 = GW1 + (size_t)FG1 * 1024;
  constexpr size_t CW1 = CW0 + (size_t)FC0 * 1024;
  constexpr size_t XEO = CW1 + (size_t)FC1 * 1024;
  constexpr size_t ACG = XEO + (size_t)B_ * S_ * E_ * 2;   // 262144 fp32
  constexpr size_t ACC = ACG + 262144 * 4;                  // 131072 fp32
  constexpr size_t CNT = ACC + 131072 * 4;                  // 64 u32
  constexpr size_t NEED = CNT + 256;
  if (ws_size < NEED) return;  // ~48.5 MB

  (void)hipFuncSetAttribute((const void*)gru_persistent,
                            hipFuncAttributeMaxDynamicSharedMemorySize, LDS_BYTES);

  init_cnt_kernel<<<1, 64, 0, stream>>>((u32*)(ws + CNT));
  zero_acc_kernel<<<1536, 256, 0, stream>>>((float*)(ws + ACG), (float*)(ws + ACC));
  pack_gw<<<FG0 / 4, 256, 0, stream>>>(Wg0, (u64*)(ws + GW0), 5, 2048, 0, FG0);
  pack_gw<<<FG1 / 4, 256, 0, stream>>>(Wg1, (u64*)(ws + GW1), 8, 2048, 1, FG1);
  pack_cw<<<FC0 / 4, 256, 0, stream>>>(Wc0, (u64*)(ws + CW0), 5, 0, FC0);
  pack_cw<<<FC1 / 4, 256, 0, stream>>>(Wc1, (u64*)(ws + CW1), 8, 1, FC1);
  pack_xe_kernel<<<B_ * S_, E_, 0, stream>>>(x, emb, (u16*)(ws + XEO));

  gru_persistent<<<NWG, 256, LDS_BYTES, stream>>>(
      (const u16*)(ws + XEO),
      (const f16x8*)(ws + GW0), (const f16x8*)(ws + GW1),
      (const f16x8*)(ws + CW0), (const f16x8*)(ws + CW1),
      bg0, bc0, bg1, bc1, h00, h01,
      (float*)(ws + ACG), (float*)(ws + ACC), (u32*)(ws + CNT), out);
}